// Round 6
// baseline (291.266 us; speedup 1.0000x reference)
//
#include <hip/hip_runtime.h>
#include <stdint.h>

#define BATCH 32
#define SEQ   1024
#define DIM   64
#define NKT   (SEQ / 64)
#define SCALE_LOG2E 0.180336879f   // (1/8) * log2(e)

typedef uint16_t u16;
typedef uint32_t u32;
typedef unsigned long long u64;
typedef __attribute__((ext_vector_type(8))) __bf16 bf16x8;
typedef __attribute__((ext_vector_type(4))) float  f32x4;
typedef __attribute__((ext_vector_type(4))) u32    u32x4;
typedef __attribute__((ext_vector_type(2))) u32    u32x2;

__device__ __forceinline__ u16 f2bf(float f) {
    u32 x = __builtin_bit_cast(u32, f);
    x += 0x7FFFu + ((x >> 16) & 1u);   // RNE
    return (u16)(x >> 16);
}
__device__ __forceinline__ bf16x8 ldg8(const u16* p) {
    u32x4 u = *reinterpret_cast<const u32x4*>(p);
    return __builtin_bit_cast(bf16x8, u);
}
__device__ __forceinline__ bf16x8 cvt8(const float* __restrict__ p) {
    f32x4 a = *reinterpret_cast<const f32x4*>(p);
    f32x4 b = *reinterpret_cast<const f32x4*>(p + 4);
    u16 t[8];
    t[0]=f2bf(a[0]); t[1]=f2bf(a[1]); t[2]=f2bf(a[2]); t[3]=f2bf(a[3]);
    t[4]=f2bf(b[0]); t[5]=f2bf(b[1]); t[6]=f2bf(b[2]); t[7]=f2bf(b[3]);
    return __builtin_bit_cast(bf16x8, *reinterpret_cast<u32x4*>(t));
}

// ---------------------------------------------------------------------------
// Pre-pass A: pack int32 mask -> bit mask (bit i of word w = mask[64w+i]!=0).
// Pure streaming: 134 MB read, 4 MB write. 4096 waves x 128 words each.
// ---------------------------------------------------------------------------
__global__ __launch_bounds__(256) void pack_mask(const int* __restrict__ m,
                                                 u64* __restrict__ pm) {
    const int lane = threadIdx.x & 63;
    const int wid  = (blockIdx.x * 256 + (int)threadIdx.x) >> 6;   // 0..4095
    const int w0   = wid * 128;
#pragma unroll 2
    for (int it = 0; it < 32; ++it) {
        int wb = w0 + it * 4;
        const int* p = m + (size_t)wb * 64 + lane;
        int x0 = p[0], x1 = p[64], x2 = p[128], x3 = p[192];
        u64 b0 = __ballot(x0 != 0);
        u64 b1 = __ballot(x1 != 0);
        u64 b2 = __ballot(x2 != 0);
        u64 b3 = __ballot(x3 != 0);
        if (lane == 0) { pm[wb]=b0; pm[wb+1]=b1; pm[wb+2]=b2; pm[wb+3]=b3; }
    }
}

// ---------------------------------------------------------------------------
// Pre-pass B: f32 -> bf16 (optionally scaled). n4 = n/4 rounded up, guarded.
// ---------------------------------------------------------------------------
__global__ __launch_bounds__(256) void cvt_bf16(const float* __restrict__ src,
                                                u16* __restrict__ dst,
                                                int n4, float scale) {
    int i = blockIdx.x * 256 + threadIdx.x;
    if (i >= n4) return;
    f32x4 a = *reinterpret_cast<const f32x4*>(src + (size_t)i * 4);
    u16 t[4] = { f2bf(a[0]*scale), f2bf(a[1]*scale), f2bf(a[2]*scale), f2bf(a[3]*scale) };
    *reinterpret_cast<u32x2*>(dst + (size_t)i * 4) = *reinterpret_cast<u32x2*>(t);
}

// ---------------------------------------------------------------------------
// Pre-pass C: V f32 [B][S][D] -> Vt bf16 [B][D][S].
// ---------------------------------------------------------------------------
__global__ __launch_bounds__(256) void vt_kernel(const float* __restrict__ v,
                                                 u16* __restrict__ vt) {
    __shared__ u16 tile[64][72];
    const int b  = blockIdx.y;
    const int k0 = blockIdx.x * 64;
    const int t  = threadIdx.x;
    const float* vb  = v  + (size_t)b * SEQ * DIM;
    u16*         vtb = vt + (size_t)b * DIM * SEQ;
    {
        int kk = t >> 2, d0 = (t & 3) * 16;
        const float* src = vb + (size_t)(k0 + kk) * DIM + d0;
        u16 tmp[16];
#pragma unroll
        for (int i = 0; i < 4; ++i) {
            f32x4 a = *reinterpret_cast<const f32x4*>(src + i * 4);
            tmp[i*4+0]=f2bf(a[0]); tmp[i*4+1]=f2bf(a[1]);
            tmp[i*4+2]=f2bf(a[2]); tmp[i*4+3]=f2bf(a[3]);
        }
        *reinterpret_cast<u32x4*>(&tile[kk][d0])     = *reinterpret_cast<u32x4*>(tmp);
        *reinterpret_cast<u32x4*>(&tile[kk][d0 + 8]) = *reinterpret_cast<u32x4*>(tmp + 8);
    }
    __syncthreads();
#pragma unroll
    for (int i = 0; i < 2; ++i) {
        int d  = t / 8 + i * 32;
        int ks = (t % 8) * 8;
        u16 tmp[8];
#pragma unroll
        for (int j = 0; j < 8; ++j) tmp[j] = tile[ks + j][d];
        *reinterpret_cast<u32x4*>(vtb + (size_t)d * SEQ + k0 + ks) =
            *reinterpret_cast<u32x4*>(tmp);
    }
}

// ---------------------------------------------------------------------------
// Main: rel-pos attention. 128-thr blocks (2 waves x 16 q-rows), grid (32,32).
// All bf16 pre-converted, mask pre-packed to bits, Q pre-scaled by log2e/8.
// No online max (logits statistically bounded, exp2 safe). No barriers in loop.
// ---------------------------------------------------------------------------
__global__ __launch_bounds__(128) void attn2(
    const u16* __restrict__ qb, const u16* __restrict__ kb,
    const u16* __restrict__ vt, const u64* __restrict__ pm,
    const u16* __restrict__ ptb, float* __restrict__ outg) {
    __shared__ float qp[2][16][132];   // 16.9 KB: q . pos_table (pre-scaled)
    __shared__ u16   plds[2][16][72];  //  4.6 KB: P C-layout -> A-layout bridge

    const int b    = blockIdx.y;
    const int q0   = blockIdx.x * 32;
    const int wave = threadIdx.x >> 6;
    const int lane = threadIdx.x & 63;
    const int quad = lane >> 4;
    const int c16  = lane & 15;
    const int rw0  = q0 + wave * 16;

    // Q A-fragments (pre-scaled bf16): lane holds A[m=c16][k=quad*8+j (+32)]
    const u16* qrow = qb + ((size_t)b * SEQ + rw0 + c16) * DIM;
    const bf16x8 qA0 = ldg8(qrow + quad * 8);
    const bf16x8 qA1 = ldg8(qrow + 32 + quad * 8);

    // qp[row][j] = (scaled q[row]) . pos_table[j], j in [0,129)
    for (int jt = 0; jt < 9; ++jt) {
        int jr = min(jt * 16 + c16, 128);
        const u16* pr = ptb + (size_t)jr * DIM;
        bf16x8 b0 = ldg8(pr + quad * 8);
        bf16x8 b1 = ldg8(pr + 32 + quad * 8);
        f32x4 acc = {0.f, 0.f, 0.f, 0.f};
        acc = __builtin_amdgcn_mfma_f32_16x16x32_bf16(qA0, b0, acc, 0, 0, 0);
        acc = __builtin_amdgcn_mfma_f32_16x16x32_bf16(qA1, b1, acc, 0, 0, 0);
        int jc = jt * 16 + c16;
        if (jc <= 128) {
#pragma unroll
            for (int r = 0; r < 4; ++r) qp[wave][quad * 4 + r][jc] = acc[r];
        }
    }

    const u16* kbb = kb + (size_t)b * SEQ * DIM;
    const u16* vtb = vt + (size_t)b * DIM * SEQ;
    const u64* pmb = pm + ((size_t)b * SEQ + rw0) * 16;

    // prologue prefetch: K tile 0, mask chunk 0
    bf16x8 kcur[8];
    u32 mlo[4], mhi[4];
#pragma unroll
    for (int sub = 0; sub < 4; ++sub) {
        const u16* base = kbb + (size_t)(sub * 16 + c16) * DIM;
        kcur[2*sub]   = ldg8(base + quad * 8);
        kcur[2*sub+1] = ldg8(base + 32 + quad * 8);
    }
#pragma unroll
    for (int r = 0; r < 4; ++r) {
        u64 w = pmb[(size_t)(quad * 4 + r) * 16];
        mlo[r] = (u32)w; mhi[r] = (u32)(w >> 32);
    }

    float lrun[4] = {0.f, 0.f, 0.f, 0.f};
    f32x4 O[4];
#pragma unroll
    for (int d = 0; d < 4; ++d) O[d] = f32x4{0.f, 0.f, 0.f, 0.f};

#pragma unroll 1
    for (int kt = 0; kt < NKT; ++kt) {
        const int k0 = kt * 64;

        // Vt frags for current tile (used at iter end -> latency hidden)
        bf16x8 vf[8];
#pragma unroll
        for (int d = 0; d < 4; ++d) {
            const u16* vbase = vtb + (size_t)(d * 16 + c16) * SEQ + k0;
            vf[2*d]   = ldg8(vbase + quad * 8);
            vf[2*d+1] = ldg8(vbase + 32 + quad * 8);
        }
        // prefetch next K tile + mask chunk
        bf16x8 kn[8];
        u32 nlo[4], nhi[4];
        {
            int ktn = (kt < NKT - 1) ? kt + 1 : kt;
            int kn0 = ktn * 64;
#pragma unroll
            for (int sub = 0; sub < 4; ++sub) {
                const u16* base = kbb + (size_t)(kn0 + sub * 16 + c16) * DIM;
                kn[2*sub]   = ldg8(base + quad * 8);
                kn[2*sub+1] = ldg8(base + 32 + quad * 8);
            }
#pragma unroll
            for (int r = 0; r < 4; ++r) {
                u64 w = pmb[(size_t)(quad * 4 + r) * 16 + ktn];
                nlo[r] = (u32)w; nhi[r] = (u32)(w >> 32);
            }
        }

        // S = (scaled Q) . K^T
        f32x4 S[4];
#pragma unroll
        for (int sub = 0; sub < 4; ++sub) {
            f32x4 acc = {0.f, 0.f, 0.f, 0.f};
            acc = __builtin_amdgcn_mfma_f32_16x16x32_bf16(qA0, kcur[2*sub],   acc, 0, 0, 0);
            acc = __builtin_amdgcn_mfma_f32_16x16x32_bf16(qA1, kcur[2*sub+1], acc, 0, 0, 0);
            S[sub] = acc;
        }

        // P = exp2(S + qp) (masked -> 0); accumulate l; store P tile (bf16)
#pragma unroll
        for (int r = 0; r < 4; ++r) {
            int row_l = quad * 4 + r;
            int row_g = rw0 + row_l;
#pragma unroll
            for (int sub = 0; sub < 4; ++sub) {
                int col = k0 + sub * 16 + c16;
                int rel = col - row_g;
                rel = rel < -64 ? -64 : (rel > 64 ? 64 : rel);
                float x = S[sub][r] + qp[wave][row_l][rel + 64];
                float e = exp2f(x);
                u32 mb = (sub & 2) ? mhi[r] : mlo[r];
                u32 bit = (mb >> ((sub & 1) * 16 + c16)) & 1u;
                e = bit ? 0.f : e;
                lrun[r] += e;
                plds[wave][row_l][sub * 16 + c16] = f2bf(e);
            }
        }

        // P -> A-layout; PV accumulate
        bf16x8 pA0 = *reinterpret_cast<bf16x8*>(&plds[wave][c16][quad * 8]);
        bf16x8 pA1 = *reinterpret_cast<bf16x8*>(&plds[wave][c16][32 + quad * 8]);
#pragma unroll
        for (int d = 0; d < 4; ++d) {
            O[d] = __builtin_amdgcn_mfma_f32_16x16x32_bf16(pA0, vf[2*d],   O[d], 0, 0, 0);
            O[d] = __builtin_amdgcn_mfma_f32_16x16x32_bf16(pA1, vf[2*d+1], O[d], 0, 0, 0);
        }
#pragma unroll
        for (int i = 0; i < 8; ++i) kcur[i] = kn[i];
#pragma unroll
        for (int r = 0; r < 4; ++r) { mlo[r] = nlo[r]; mhi[r] = nhi[r]; }
    }

    // epilogue: reduce l across the 16 lanes holding each row; write f32
    float* ob = outg + ((size_t)b * SEQ + rw0) * DIM;
#pragma unroll
    for (int r = 0; r < 4; ++r) {
        float l = lrun[r];
        l += __shfl_xor(l, 1);
        l += __shfl_xor(l, 2);
        l += __shfl_xor(l, 4);
        l += __shfl_xor(l, 8);
        float inv = 1.f / l;
        int row_l = quad * 4 + r;
#pragma unroll
        for (int d = 0; d < 4; ++d)
            ob[(size_t)row_l * DIM + d * 16 + c16] = O[d][r] * inv;
    }
}

// ---------------------------------------------------------------------------
// Fallback (R5-proven, ws-free): f32 inputs, in-kernel cvt, scalar V.
// ---------------------------------------------------------------------------
__global__ __launch_bounds__(256, 2) void attn_fb(
    const float* __restrict__ qg, const float* __restrict__ kg,
    const float* __restrict__ vg, const int* __restrict__ maskg,
    const float* __restrict__ ptg, float* __restrict__ outg) {
    __shared__ float qp[64][132];
    __shared__ int   mlds[4][16][68];
    __shared__ u16   plds[4][16][72];

    const int b = blockIdx.y, q0 = blockIdx.x * 64;
    const int tid = threadIdx.x, wave = tid >> 6, lane = tid & 63;
    const int quad = lane >> 4, c16 = lane & 15;

    const float* qb2 = qg + ((size_t)b * SEQ + q0) * DIM;
    const float* kb2 = kg + (size_t)b * SEQ * DIM;
    const int*   mb  = maskg + ((size_t)b * SEQ + q0) * SEQ;

    const bf16x8 qA0 = cvt8(qb2 + (size_t)(wave*16 + c16) * DIM + quad * 8);
    const bf16x8 qA1 = cvt8(qb2 + (size_t)(wave*16 + c16) * DIM + 32 + quad * 8);

    for (int jt = 0; jt < 9; ++jt) {
        int jr = min(jt * 16 + c16, 128);
        bf16x8 b0 = cvt8(ptg + (size_t)jr * DIM + quad * 8);
        bf16x8 b1 = cvt8(ptg + (size_t)jr * DIM + 32 + quad * 8);
        f32x4 acc = {0.f,0.f,0.f,0.f};
        acc = __builtin_amdgcn_mfma_f32_16x16x32_bf16(qA0, b0, acc, 0,0,0);
        acc = __builtin_amdgcn_mfma_f32_16x16x32_bf16(qA1, b1, acc, 0,0,0);
        int jc = jt * 16 + c16;
        if (jc <= 128) {
#pragma unroll
            for (int r = 0; r < 4; ++r) qp[wave*16 + quad*4 + r][jc] = acc[r];
        }
    }
    float m_run[4], l_run[4];
    f32x4 O[4];
#pragma unroll
    for (int r = 0; r < 4; ++r) { m_run[r] = -1e30f; l_run[r] = 0.f; }
#pragma unroll
    for (int d = 0; d < 4; ++d) O[d] = f32x4{0.f,0.f,0.f,0.f};

#pragma unroll 1
    for (int kt = 0; kt < NKT; ++kt) {
        const int k0 = kt * 64;
        {
            int row_l = lane >> 2;
            const int* mrow = mb + (size_t)(wave*16 + row_l) * SEQ + k0;
#pragma unroll
            for (int i = 0; i < 4; ++i) {
                int seg = (lane & 3) + i * 4;
                *reinterpret_cast<u32x4*>(&mlds[wave][row_l][seg*4]) =
                    *reinterpret_cast<const u32x4*>(mrow + seg*4);
            }
        }
        f32x4 S[4];
#pragma unroll
        for (int sub = 0; sub < 4; ++sub) {
            const float* kr = kb2 + (size_t)(k0 + sub*16 + c16) * DIM;
            bf16x8 kb0 = cvt8(kr + quad*8), kb1 = cvt8(kr + 32 + quad*8);
            f32x4 acc = {0.f,0.f,0.f,0.f};
            acc = __builtin_amdgcn_mfma_f32_16x16x32_bf16(qA0, kb0, acc, 0,0,0);
            acc = __builtin_amdgcn_mfma_f32_16x16x32_bf16(qA1, kb1, acc, 0,0,0);
            S[sub] = acc;
        }
        float sv[4][4];
#pragma unroll
        for (int sub = 0; sub < 4; ++sub)
#pragma unroll
            for (int r = 0; r < 4; ++r) {
                int row_l = quad*4 + r, row_g = q0 + wave*16 + row_l;
                int col = k0 + sub*16 + c16;
                int rel = col - row_g; rel = rel < -64 ? -64 : (rel > 64 ? 64 : rel);
                float x = (S[sub][r] + qp[wave*16 + row_l][rel + 64]) * 0.125f;
                sv[sub][r] = mlds[wave][row_l][sub*16 + c16] ? -1e30f : x;
            }
        float m_new[4], alpha[4];
#pragma unroll
        for (int r = 0; r < 4; ++r) {
            float rm = fmaxf(fmaxf(sv[0][r], sv[1][r]), fmaxf(sv[2][r], sv[3][r]));
            rm = fmaxf(rm, __shfl_xor(rm, 1)); rm = fmaxf(rm, __shfl_xor(rm, 2));
            rm = fmaxf(rm, __shfl_xor(rm, 4)); rm = fmaxf(rm, __shfl_xor(rm, 8));
            m_new[r] = fmaxf(m_run[r], rm);
            alpha[r] = __expf(m_run[r] - m_new[r]);
            m_run[r] = m_new[r];
        }
#pragma unroll
        for (int r = 0; r < 4; ++r) {
            float rs = 0.f;
#pragma unroll
            for (int sub = 0; sub < 4; ++sub) {
                float e = __expf(sv[sub][r] - m_new[r]);
                rs += e;
                plds[wave][quad*4 + r][sub*16 + c16] = f2bf(e);
            }
            rs += __shfl_xor(rs, 1); rs += __shfl_xor(rs, 2);
            rs += __shfl_xor(rs, 4); rs += __shfl_xor(rs, 8);
            l_run[r] = l_run[r] * alpha[r] + rs;
#pragma unroll
            for (int d = 0; d < 4; ++d) O[d][r] *= alpha[r];
        }
        bf16x8 pA0 = *reinterpret_cast<bf16x8*>(&plds[wave][c16][quad*8]);
        bf16x8 pA1 = *reinterpret_cast<bf16x8*>(&plds[wave][c16][32 + quad*8]);
#pragma unroll
        for (int d = 0; d < 4; ++d) {
            u16 t0[8], t1[8];
            const float* vb2 = vg + ((size_t)b * SEQ + k0) * DIM + d*16 + c16;
#pragma unroll
            for (int j = 0; j < 8; ++j) {
                t0[j] = f2bf(vb2[(size_t)(quad*8 + j) * DIM]);
                t1[j] = f2bf(vb2[(size_t)(32 + quad*8 + j) * DIM]);
            }
            bf16x8 vb0 = __builtin_bit_cast(bf16x8, *reinterpret_cast<u32x4*>(t0));
            bf16x8 vb1 = __builtin_bit_cast(bf16x8, *reinterpret_cast<u32x4*>(t1));
            O[d] = __builtin_amdgcn_mfma_f32_16x16x32_bf16(pA0, vb0, O[d], 0,0,0);
            O[d] = __builtin_amdgcn_mfma_f32_16x16x32_bf16(pA1, vb1, O[d], 0,0,0);
        }
    }
    float* ob = outg + ((size_t)b * SEQ + q0) * DIM;
#pragma unroll
    for (int r = 0; r < 4; ++r) {
        float inv = 1.f / l_run[r];
        int row_l = wave*16 + quad*4 + r;
#pragma unroll
        for (int d = 0; d < 4; ++d)
            ob[(size_t)row_l * DIM + d*16 + c16] = O[d][r] * inv;
    }
}

// ---------------------------------------------------------------------------
extern "C" void kernel_launch(void* const* d_in, const int* in_sizes, int n_in,
                              void* d_out, int out_size, void* d_ws, size_t ws_size,
                              hipStream_t stream) {
    const float* q    = (const float*)d_in[0];
    const float* k    = (const float*)d_in[1];
    const float* v    = (const float*)d_in[2];
    const int*   mask = (const int*)d_in[3];
    const float* pt   = (const float*)d_in[4];
    float* out        = (float*)d_out;

    const size_t PM_B = (size_t)BATCH * SEQ * (SEQ / 64) * 8;      // 4 MB
    const size_t VT_B = (size_t)BATCH * SEQ * DIM * 2;             // 4 MB
    const size_t QB_B = VT_B, KB_B = VT_B;
    const size_t PT_B = 32768;
    const size_t need = PM_B + VT_B + QB_B + KB_B + PT_B;

    if (ws_size >= need) {
        char* w = (char*)d_ws;
        u64* pmp = (u64*)w;  w += PM_B;
        u16* vtp = (u16*)w;  w += VT_B;
        u16* qbp = (u16*)w;  w += QB_B;
        u16* kbp = (u16*)w;  w += KB_B;
        u16* ptp = (u16*)w;

        pack_mask<<<1024, 256, 0, stream>>>(mask, pmp);
        cvt_bf16<<<2048, 256, 0, stream>>>(q, qbp, 524288, SCALE_LOG2E);
        cvt_bf16<<<2048, 256, 0, stream>>>(k, kbp, 524288, 1.0f);
        cvt_bf16<<<9,    256, 0, stream>>>(pt, ptp, 2064, 1.0f);
        vt_kernel<<<dim3(SEQ / 64, BATCH), 256, 0, stream>>>(v, vtp);
        attn2<<<dim3(SEQ / 32, BATCH), 128, 0, stream>>>(qbp, kbp, vtp, pmp, ptp, out);
    } else {
        attn_fb<<<dim3(SEQ / 64, BATCH), 256, 0, stream>>>(q, k, v, mask, pt, out);
    }
}

// Round 9
// 283.602 us; speedup vs baseline: 1.0270x; 1.0270x over previous
//
#include <hip/hip_runtime.h>
#include <stdint.h>

#define BATCH 32
#define SEQ   1024
#define DIM   64
#define NKT   (SEQ / 64)
#define SCALE_LOG2E 0.180336879f   // (1/8) * log2(e)

typedef uint16_t u16;
typedef uint32_t u32;
typedef unsigned long long u64;
typedef __attribute__((ext_vector_type(8))) __bf16 bf16x8;
typedef __attribute__((ext_vector_type(4))) float  f32x4;
typedef __attribute__((ext_vector_type(4))) u32    u32x4;
typedef __attribute__((ext_vector_type(2))) u32    u32x2;

__device__ __forceinline__ u16 f2bf(float f) {
    u32 x = __builtin_bit_cast(u32, f);
    x += 0x7FFFu + ((x >> 16) & 1u);   // RNE
    return (u16)(x >> 16);
}
__device__ __forceinline__ bf16x8 ldg8(const u16* p) {
    u32x4 u = *reinterpret_cast<const u32x4*>(p);
    return __builtin_bit_cast(bf16x8, u);
}
__device__ __forceinline__ bf16x8 cvt8(const float* __restrict__ p) {
    f32x4 a = *reinterpret_cast<const f32x4*>(p);
    f32x4 b = *reinterpret_cast<const f32x4*>(p + 4);
    u16 t[8];
    t[0]=f2bf(a[0]); t[1]=f2bf(a[1]); t[2]=f2bf(a[2]); t[3]=f2bf(a[3]);
    t[4]=f2bf(b[0]); t[5]=f2bf(b[1]); t[6]=f2bf(b[2]); t[7]=f2bf(b[3]);
    return __builtin_bit_cast(bf16x8, *reinterpret_cast<u32x4*>(t));
}

// ---------------------------------------------------------------------------
// ONE fused prepass kernel (full-coverage version, R8-verified arithmetic).
// blocks [0,1024):    pack int32 mask -> bit mask
// blocks [1024,1536): q f32 -> bf16 scaled (4 strided chunks -> FULL q)
// blocks [1536,2048): k f32 -> bf16 (FULL k)
// blocks [2048,2057): pos_table f32 -> bf16
// blocks [2057,2569): V f32 [B][S][D] -> Vt bf16 [B][D][S]
// ---------------------------------------------------------------------------
__global__ __launch_bounds__(256) void prep(
    const int* __restrict__ m, const float* __restrict__ q,
    const float* __restrict__ k, const float* __restrict__ pt,
    const float* __restrict__ v,
    u64* __restrict__ pm, u16* __restrict__ qb, u16* __restrict__ kb,
    u16* __restrict__ ptb, u16* __restrict__ vt) {
    __shared__ u16 tile[64][72];
    const int blk = blockIdx.x;
    const int tid = threadIdx.x;

    if (blk < 1024) {                       // ---- mask pack ----
        const int lane = tid & 63;
        const int wid  = (blk * 256 + tid) >> 6;   // 0..4095
        const int w0   = wid * 128;
#pragma unroll 2
        for (int it = 0; it < 32; ++it) {
            int wb = w0 + it * 4;
            const int* p = m + (size_t)wb * 64 + lane;
            int x0 = p[0], x1 = p[64], x2 = p[128], x3 = p[192];
            u64 b0 = __ballot(x0 != 0);
            u64 b1 = __ballot(x1 != 0);
            u64 b2 = __ballot(x2 != 0);
            u64 b3 = __ballot(x3 != 0);
            if (lane == 0) { pm[wb]=b0; pm[wb+1]=b1; pm[wb+2]=b2; pm[wb+3]=b3; }
        }
    } else if (blk < 1536) {                // ---- q cvt (scaled), FULL ----
        int i0 = (blk - 1024) * 256 + tid;
#pragma unroll
        for (int it = 0; it < 4; ++it) {
            int i = i0 + it * 131072;
            f32x4 a = *reinterpret_cast<const f32x4*>(q + (size_t)i * 4);
            u16 t[4] = { f2bf(a[0]*SCALE_LOG2E), f2bf(a[1]*SCALE_LOG2E),
                         f2bf(a[2]*SCALE_LOG2E), f2bf(a[3]*SCALE_LOG2E) };
            *reinterpret_cast<u32x2*>(qb + (size_t)i * 4) = *reinterpret_cast<u32x2*>(t);
        }
    } else if (blk < 2048) {                // ---- k cvt, FULL ----
        int i0 = (blk - 1536) * 256 + tid;
#pragma unroll
        for (int it = 0; it < 4; ++it) {
            int i = i0 + it * 131072;
            f32x4 a = *reinterpret_cast<const f32x4*>(k + (size_t)i * 4);
            u16 t[4] = { f2bf(a[0]), f2bf(a[1]), f2bf(a[2]), f2bf(a[3]) };
            *reinterpret_cast<u32x2*>(kb + (size_t)i * 4) = *reinterpret_cast<u32x2*>(t);
        }
    } else if (blk < 2057) {                // ---- pos_table cvt ----
        int i = (blk - 2048) * 256 + tid;
        if (i < 2064) {
            f32x4 a = *reinterpret_cast<const f32x4*>(pt + (size_t)i * 4);
            u16 t[4] = { f2bf(a[0]), f2bf(a[1]), f2bf(a[2]), f2bf(a[3]) };
            *reinterpret_cast<u32x2*>(ptb + (size_t)i * 4) = *reinterpret_cast<u32x2*>(t);
        }
    } else {                                // ---- V transpose ----
        int j  = blk - 2057;                // 0..511
        int b  = j >> 4;
        int k0 = (j & 15) << 6;
        const float* vb  = v  + (size_t)b * SEQ * DIM;
        u16*         vtb = vt + (size_t)b * DIM * SEQ;
        {
            int kk = tid >> 2, d0 = (tid & 3) * 16;
            const float* src = vb + (size_t)(k0 + kk) * DIM + d0;
            u16 tmp[16];
#pragma unroll
            for (int i = 0; i < 4; ++i) {
                f32x4 a = *reinterpret_cast<const f32x4*>(src + i * 4);
                tmp[i*4+0]=f2bf(a[0]); tmp[i*4+1]=f2bf(a[1]);
                tmp[i*4+2]=f2bf(a[2]); tmp[i*4+3]=f2bf(a[3]);
            }
            *reinterpret_cast<u32x4*>(&tile[kk][d0])     = *reinterpret_cast<u32x4*>(tmp);
            *reinterpret_cast<u32x4*>(&tile[kk][d0 + 8]) = *reinterpret_cast<u32x4*>(tmp + 8);
        }
        __syncthreads();
#pragma unroll
        for (int i = 0; i < 2; ++i) {
            int d  = tid / 8 + i * 32;
            int ks = (tid % 8) * 8;
            u16 tmp[8];
#pragma unroll
            for (int jj = 0; jj < 8; ++jj) tmp[jj] = tile[ks + jj][d];
            *reinterpret_cast<u32x4*>(vtb + (size_t)d * SEQ + k0 + ks) =
                *reinterpret_cast<u32x4*>(tmp);
        }
    }
}

// ---------------------------------------------------------------------------
// Main attention — R6-PROVEN attn2, verbatim. 128-thr blocks (2 waves x 16
// q-rows each, full K range per wave). Grid (SEQ/32, BATCH).
// ---------------------------------------------------------------------------
__global__ __launch_bounds__(128) void attn2(
    const u16* __restrict__ qb, const u16* __restrict__ kb,
    const u16* __restrict__ vt, const u64* __restrict__ pm,
    const u16* __restrict__ ptb, float* __restrict__ outg) {
    __shared__ float qp[2][16][132];   // 16.9 KB: q . pos_table (pre-scaled)
    __shared__ u16   plds[2][16][72];  //  4.6 KB: P C-layout -> A-layout bridge

    const int b    = blockIdx.y;
    const int q0   = blockIdx.x * 32;
    const int wave = threadIdx.x >> 6;
    const int lane = threadIdx.x & 63;
    const int quad = lane >> 4;
    const int c16  = lane & 15;
    const int rw0  = q0 + wave * 16;

    // Q A-fragments (pre-scaled bf16): lane holds A[m=c16][k=quad*8+j (+32)]
    const u16* qrow = qb + ((size_t)b * SEQ + rw0 + c16) * DIM;
    const bf16x8 qA0 = ldg8(qrow + quad * 8);
    const bf16x8 qA1 = ldg8(qrow + 32 + quad * 8);

    // qp[row][j] = (scaled q[row]) . pos_table[j], j in [0,129)
    for (int jt = 0; jt < 9; ++jt) {
        int jr = min(jt * 16 + c16, 128);
        const u16* pr = ptb + (size_t)jr * DIM;
        bf16x8 b0 = ldg8(pr + quad * 8);
        bf16x8 b1 = ldg8(pr + 32 + quad * 8);
        f32x4 acc = {0.f, 0.f, 0.f, 0.f};
        acc = __builtin_amdgcn_mfma_f32_16x16x32_bf16(qA0, b0, acc, 0, 0, 0);
        acc = __builtin_amdgcn_mfma_f32_16x16x32_bf16(qA1, b1, acc, 0, 0, 0);
        int jc = jt * 16 + c16;
        if (jc <= 128) {
#pragma unroll
            for (int r = 0; r < 4; ++r) qp[wave][quad * 4 + r][jc] = acc[r];
        }
    }

    const u16* kbb = kb + (size_t)b * SEQ * DIM;
    const u16* vtb = vt + (size_t)b * DIM * SEQ;
    const u64* pmb = pm + ((size_t)b * SEQ + rw0) * 16;

    // prologue prefetch: K tile 0, mask chunk 0
    bf16x8 kcur[8];
    u32 mlo[4], mhi[4];
#pragma unroll
    for (int sub = 0; sub < 4; ++sub) {
        const u16* base = kbb + (size_t)(sub * 16 + c16) * DIM;
        kcur[2*sub]   = ldg8(base + quad * 8);
        kcur[2*sub+1] = ldg8(base + 32 + quad * 8);
    }
#pragma unroll
    for (int r = 0; r < 4; ++r) {
        u64 w = pmb[(size_t)(quad * 4 + r) * 16];
        mlo[r] = (u32)w; mhi[r] = (u32)(w >> 32);
    }

    float lrun[4] = {0.f, 0.f, 0.f, 0.f};
    f32x4 O[4];
#pragma unroll
    for (int d = 0; d < 4; ++d) O[d] = f32x4{0.f, 0.f, 0.f, 0.f};

#pragma unroll 1
    for (int kt = 0; kt < NKT; ++kt) {
        const int k0 = kt * 64;

        // Vt frags for current tile (used at iter end -> latency hidden)
        bf16x8 vf[8];
#pragma unroll
        for (int d = 0; d < 4; ++d) {
            const u16* vbase = vtb + (size_t)(d * 16 + c16) * SEQ + k0;
            vf[2*d]   = ldg8(vbase + quad * 8);
            vf[2*d+1] = ldg8(vbase + 32 + quad * 8);
        }
        // prefetch next K tile + mask chunk
        bf16x8 kn[8];
        u32 nlo[4], nhi[4];
        {
            int ktn = (kt < NKT - 1) ? kt + 1 : kt;
            int kn0 = ktn * 64;
#pragma unroll
            for (int sub = 0; sub < 4; ++sub) {
                const u16* base = kbb + (size_t)(kn0 + sub * 16 + c16) * DIM;
                kn[2*sub]   = ldg8(base + quad * 8);
                kn[2*sub+1] = ldg8(base + 32 + quad * 8);
            }
#pragma unroll
            for (int r = 0; r < 4; ++r) {
                u64 w = pmb[(size_t)(quad * 4 + r) * 16 + ktn];
                nlo[r] = (u32)w; nhi[r] = (u32)(w >> 32);
            }
        }

        // S = (scaled Q) . K^T
        f32x4 S[4];
#pragma unroll
        for (int sub = 0; sub < 4; ++sub) {
            f32x4 acc = {0.f, 0.f, 0.f, 0.f};
            acc = __builtin_amdgcn_mfma_f32_16x16x32_bf16(qA0, kcur[2*sub],   acc, 0, 0, 0);
            acc = __builtin_amdgcn_mfma_f32_16x16x32_bf16(qA1, kcur[2*sub+1], acc, 0, 0, 0);
            S[sub] = acc;
        }

        // P = exp2(S + qp) (masked -> 0); accumulate l; store P tile (bf16)
#pragma unroll
        for (int r = 0; r < 4; ++r) {
            int row_l = quad * 4 + r;
            int row_g = rw0 + row_l;
#pragma unroll
            for (int sub = 0; sub < 4; ++sub) {
                int col = k0 + sub * 16 + c16;
                int rel = col - row_g;
                rel = rel < -64 ? -64 : (rel > 64 ? 64 : rel);
                float x = S[sub][r] + qp[wave][row_l][rel + 64];
                float e = exp2f(x);
                u32 mb = (sub & 2) ? mhi[r] : mlo[r];
                u32 bit = (mb >> ((sub & 1) * 16 + c16)) & 1u;
                e = bit ? 0.f : e;
                lrun[r] += e;
                plds[wave][row_l][sub * 16 + c16] = f2bf(e);
            }
        }

        // P -> A-layout; PV accumulate
        bf16x8 pA0 = *reinterpret_cast<bf16x8*>(&plds[wave][c16][quad * 8]);
        bf16x8 pA1 = *reinterpret_cast<bf16x8*>(&plds[wave][c16][32 + quad * 8]);
#pragma unroll
        for (int d = 0; d < 4; ++d) {
            O[d] = __builtin_amdgcn_mfma_f32_16x16x32_bf16(pA0, vf[2*d],   O[d], 0, 0, 0);
            O[d] = __builtin_amdgcn_mfma_f32_16x16x32_bf16(pA1, vf[2*d+1], O[d], 0, 0, 0);
        }
#pragma unroll
        for (int i = 0; i < 8; ++i) kcur[i] = kn[i];
#pragma unroll
        for (int r = 0; r < 4; ++r) { mlo[r] = nlo[r]; mhi[r] = nhi[r]; }
    }

    // epilogue: reduce l across the 16 lanes holding each row; write f32
    float* ob = outg + ((size_t)b * SEQ + rw0) * DIM;
#pragma unroll
    for (int r = 0; r < 4; ++r) {
        float l = lrun[r];
        l += __shfl_xor(l, 1);
        l += __shfl_xor(l, 2);
        l += __shfl_xor(l, 4);
        l += __shfl_xor(l, 8);
        float inv = 1.f / l;
        int row_l = quad * 4 + r;
#pragma unroll
        for (int d = 0; d < 4; ++d)
            ob[(size_t)row_l * DIM + d * 16 + c16] = O[d][r] * inv;
    }
}

// ---------------------------------------------------------------------------
// Fallback (R5-proven, ws-free).
// ---------------------------------------------------------------------------
__global__ __launch_bounds__(256, 2) void attn_fb(
    const float* __restrict__ qg, const float* __restrict__ kg,
    const float* __restrict__ vg, const int* __restrict__ maskg,
    const float* __restrict__ ptg, float* __restrict__ outg) {
    __shared__ float qp[64][132];
    __shared__ int   mlds[4][16][68];
    __shared__ u16   plds[4][16][72];

    const int b = blockIdx.y, q0 = blockIdx.x * 64;
    const int tid = threadIdx.x, wave = tid >> 6, lane = tid & 63;
    const int quad = lane >> 4, c16 = lane & 15;

    const float* qb2 = qg + ((size_t)b * SEQ + q0) * DIM;
    const float* kb2 = kg + (size_t)b * SEQ * DIM;
    const int*   mb  = maskg + ((size_t)b * SEQ + q0) * SEQ;

    const bf16x8 qA0 = cvt8(qb2 + (size_t)(wave*16 + c16) * DIM + quad * 8);
    const bf16x8 qA1 = cvt8(qb2 + (size_t)(wave*16 + c16) * DIM + 32 + quad * 8);

    for (int jt = 0; jt < 9; ++jt) {
        int jr = min(jt * 16 + c16, 128);
        bf16x8 b0 = cvt8(ptg + (size_t)jr * DIM + quad * 8);
        bf16x8 b1 = cvt8(ptg + (size_t)jr * DIM + 32 + quad * 8);
        f32x4 acc = {0.f,0.f,0.f,0.f};
        acc = __builtin_amdgcn_mfma_f32_16x16x32_bf16(qA0, b0, acc, 0,0,0);
        acc = __builtin_amdgcn_mfma_f32_16x16x32_bf16(qA1, b1, acc, 0,0,0);
        int jc = jt * 16 + c16;
        if (jc <= 128) {
#pragma unroll
            for (int r = 0; r < 4; ++r) qp[wave*16 + quad*4 + r][jc] = acc[r];
        }
    }
    float m_run[4], l_run[4];
    f32x4 O[4];
#pragma unroll
    for (int r = 0; r < 4; ++r) { m_run[r] = -1e30f; l_run[r] = 0.f; }
#pragma unroll
    for (int d = 0; d < 4; ++d) O[d] = f32x4{0.f,0.f,0.f,0.f};

#pragma unroll 1
    for (int kt = 0; kt < NKT; ++kt) {
        const int k0 = kt * 64;
        {
            int row_l = lane >> 2;
            const int* mrow = mb + (size_t)(wave*16 + row_l) * SEQ + k0;
#pragma unroll
            for (int i = 0; i < 4; ++i) {
                int seg = (lane & 3) + i * 4;
                *reinterpret_cast<u32x4*>(&mlds[wave][row_l][seg*4]) =
                    *reinterpret_cast<const u32x4*>(mrow + seg*4);
            }
        }
        f32x4 S[4];
#pragma unroll
        for (int sub = 0; sub < 4; ++sub) {
            const float* kr = kb2 + (size_t)(k0 + sub*16 + c16) * DIM;
            bf16x8 kb0 = cvt8(kr + quad*8), kb1 = cvt8(kr + 32 + quad*8);
            f32x4 acc = {0.f,0.f,0.f,0.f};
            acc = __builtin_amdgcn_mfma_f32_16x16x32_bf16(qA0, kb0, acc, 0,0,0);
            acc = __builtin_amdgcn_mfma_f32_16x16x32_bf16(qA1, kb1, acc, 0,0,0);
            S[sub] = acc;
        }
        float sv[4][4];
#pragma unroll
        for (int sub = 0; sub < 4; ++sub)
#pragma unroll
            for (int r = 0; r < 4; ++r) {
                int row_l = quad*4 + r, row_g = q0 + wave*16 + row_l;
                int col = k0 + sub*16 + c16;
                int rel = col - row_g; rel = rel < -64 ? -64 : (rel > 64 ? 64 : rel);
                float x = (S[sub][r] + qp[wave*16 + row_l][rel + 64]) * 0.125f;
                sv[sub][r] = mlds[wave][row_l][sub*16 + c16] ? -1e30f : x;
            }
        float m_new[4], alpha[4];
#pragma unroll
        for (int r = 0; r < 4; ++r) {
            float rm = fmaxf(fmaxf(sv[0][r], sv[1][r]), fmaxf(sv[2][r], sv[3][r]));
            rm = fmaxf(rm, __shfl_xor(rm, 1)); rm = fmaxf(rm, __shfl_xor(rm, 2));
            rm = fmaxf(rm, __shfl_xor(rm, 4)); rm = fmaxf(rm, __shfl_xor(rm, 8));
            m_new[r] = fmaxf(m_run[r], rm);
            alpha[r] = __expf(m_run[r] - m_new[r]);
            m_run[r] = m_new[r];
        }
#pragma unroll
        for (int r = 0; r < 4; ++r) {
            float rs = 0.f;
#pragma unroll
            for (int sub = 0; sub < 4; ++sub) {
                float e = __expf(sv[sub][r] - m_new[r]);
                rs += e;
                plds[wave][quad*4 + r][sub*16 + c16] = f2bf(e);
            }
            rs += __shfl_xor(rs, 1); rs += __shfl_xor(rs, 2);
            rs += __shfl_xor(rs, 4); rs += __shfl_xor(rs, 8);
            l_run[r] = l_run[r] * alpha[r] + rs;
#pragma unroll
            for (int d = 0; d < 4; ++d) O[d][r] *= alpha[r];
        }
        bf16x8 pA0 = *reinterpret_cast<bf16x8*>(&plds[wave][c16][quad*8]);
        bf16x8 pA1 = *reinterpret_cast<bf16x8*>(&plds[wave][c16][32 + quad*8]);
#pragma unroll
        for (int d = 0; d < 4; ++d) {
            u16 t0[8], t1[8];
            const float* vb2 = vg + ((size_t)b * SEQ + k0) * DIM + d*16 + c16;
#pragma unroll
            for (int j = 0; j < 8; ++j) {
                t0[j] = f2bf(vb2[(size_t)(quad*8 + j) * DIM]);
                t1[j] = f2bf(vb2[(size_t)(32 + quad*8 + j) * DIM]);
            }
            bf16x8 vb0 = __builtin_bit_cast(bf16x8, *reinterpret_cast<u32x4*>(t0));
            bf16x8 vb1 = __builtin_bit_cast(bf16x8, *reinterpret_cast<u32x4*>(t1));
            O[d] = __builtin_amdgcn_mfma_f32_16x16x32_bf16(pA0, vb0, O[d], 0,0,0);
            O[d] = __builtin_amdgcn_mfma_f32_16x16x32_bf16(pA1, vb1, O[d], 0,0,0);
        }
    }
    float* ob = outg + ((size_t)b * SEQ + q0) * DIM;
#pragma unroll
    for (int r = 0; r < 4; ++r) {
        float inv = 1.f / l_run[r];
        int row_l = wave*16 + quad*4 + r;
#pragma unroll
        for (int d = 0; d < 4; ++d)
            ob[(size_t)row_l * DIM + d*16 + c16] = O[d][r] * inv;
    }
}

// ---------------------------------------------------------------------------
extern "C" void kernel_launch(void* const* d_in, const int* in_sizes, int n_in,
                              void* d_out, int out_size, void* d_ws, size_t ws_size,
                              hipStream_t stream) {
    const float* q    = (const float*)d_in[0];
    const float* k    = (const float*)d_in[1];
    const float* v    = (const float*)d_in[2];
    const int*   mask = (const int*)d_in[3];
    const float* pt   = (const float*)d_in[4];
    float* out        = (float*)d_out;

    const size_t PM_B = (size_t)BATCH * SEQ * (SEQ / 64) * 8;      // 4 MB
    const size_t VT_B = (size_t)BATCH * SEQ * DIM * 2;             // 4 MB
    const size_t QB_B = VT_B, KB_B = VT_B;
    const size_t PT_B = 32768;
    const size_t need = PM_B + VT_B + QB_B + KB_B + PT_B;

    if (ws_size >= need) {
        char* w = (char*)d_ws;
        u64* pmp = (u64*)w;  w += PM_B;
        u16* vtp = (u16*)w;  w += VT_B;
        u16* qbp = (u16*)w;  w += QB_B;
        u16* kbp = (u16*)w;  w += KB_B;
        u16* ptp = (u16*)w;

        prep<<<2569, 256, 0, stream>>>(mask, q, k, pt, v, pmp, qbp, kbp, ptp, vtp);
        attn2<<<dim3(SEQ / 32, BATCH), 128, 0, stream>>>(qbp, kbp, vtp, pmp, ptp, out);
    } else {
        attn_fb<<<dim3(SEQ / 64, BATCH), 256, 0, stream>>>(q, k, v, mask, pt, out);
    }
}